// Round 11
// baseline (10.973 us; speedup 1.0000x reference)
//
#include <hip/hip_runtime.h>

// ImplicitComplexModalFilter via FP16 MFMA factorization, barrier-free form.
// K[h, 32a+b] = Re( sum_n U[a,n] * V[n,b] ),  U[a,n] = Cm_n * z_n^(32a) (64x64),
// V[n,b] = z_n^b (64x32), z_n = exp(dtA_n).
// Interleaved-complex K=128 contraction: A[a][2n]=Re U, A[a][2n+1]=-Im U;
// B^T[b][2n]=Re V, B^T[b][2n+1]=Im V  ->  sum_k A B = Re(U V).
// Round 11: ONE WAVE PER 16x16 OUTPUT TILE. Grid = 1024 h x 8 tiles; each
// 64-thread block gens only its own U/V slices into private LDS (8.5 KB),
// MFMAs, stores. Zero __syncthreads -- intra-wave lgkmcnt ordering only.
// Tests whether the 8-wave barrier-coupled phase structure was the ~10.5 us
// cost; if time is unchanged, the external ~10 us floor is confirmed.

typedef __attribute__((ext_vector_type(8))) _Float16 f16x8;
typedef __attribute__((ext_vector_type(2))) __fp16   h16x2;  // cvt_pkrtz result
typedef __attribute__((ext_vector_type(4))) float    f32x4;

#define Hdim 1024
#define Ndim 64
#define Ldim 2048
#define KPAD 136   // f16 units: 272B row stride, 16B-aligned

#define LOG2E  1.4426950408889634f
#define INV2PI 0.15915494309189535f

__device__ __forceinline__ void cmul(float& xr, float& xi, float yr, float yi) {
    const float tr = fmaf(xr, yr, -(xi * yi));
    xi = fmaf(xr, yi, xi * yr);
    xr = tr;
}

// z^t = exp(dtA * t) from ar2 = Re(dtA)*log2e, airev = Im(dtA)/2pi
__device__ __forceinline__ void expz(float ar2, float airev, float t,
                                     float& zr, float& zi) {
    const float e = __builtin_amdgcn_exp2f(ar2 * t);
    float f = airev * t;
    f -= floorf(f);
    zr = e * __builtin_amdgcn_cosf(f);
    zi = e * __builtin_amdgcn_sinf(f);
}

__global__ __launch_bounds__(64, 4) void icmf_mfma(
    const float* __restrict__ log_dt,
    const float* __restrict__ C_re, const float* __restrict__ C_im,
    const float* __restrict__ B_re, const float* __restrict__ B_im,
    const float* __restrict__ inv_A_real, const float* __restrict__ A_imag,
    float* __restrict__ out)
{
    __shared__ __align__(16) _Float16 sA[16][KPAD];  // this tile's U rows
    __shared__ __align__(16) _Float16 sB[16][KPAD];  // this tile's V rows

    const int bid  = blockIdx.x;
    const int h    = bid >> 3;
    const int tile = bid & 7;
    const int mt   = tile >> 1;   // a-tile 0..3  (a rows 16mt .. 16mt+15)
    const int nt   = tile & 1;    // b-tile 0..1  (b cols 16nt .. 16nt+15)
    const int n    = threadIdx.x; // lane = state index n (0..63)

    // ---- per-(h,n) setup + this tile's chain anchors ----
    {
        const int idx = h * Ndim + n;
        const float dt = __builtin_amdgcn_exp2f(log_dt[h] * LOG2E);
        const float ar = -dt * __builtin_amdgcn_exp2f(inv_A_real[idx] * LOG2E);
        const float ai =  dt * A_imag[idx];
        // scale = dt / (1 - dtA/2)
        const float dre = 1.0f - 0.5f * ar;
        const float dim = -0.5f * ai;
        const float kk  = dt / (dre * dre + dim * dim);
        const float sre =  dre * kk;
        const float sim = -dim * kk;
        // Cm = 2 * B*C*scale (fold final 2x)
        const float br = B_re[idx], bi = B_im[idx];
        const float cr = C_re[idx], ci = C_im[idx];
        const float bcr = br * cr - bi * ci;
        const float bci = br * ci + bi * cr;
        const float cmr = 2.0f * (bcr * sre - bci * sim);
        const float cmi = 2.0f * (bcr * sim + bci * sre);
        const float ar2   = ar * LOG2E;
        const float airev = ai * INV2PI;

        // steppers + anchors: 4 independent direct evaluations
        float z1r, z1i, z32r, z32i, vr, vi, tr_, ti_;
        expz(ar2, airev, 1.0f,               z1r,  z1i);   // V stepper
        expz(ar2, airev, 32.0f,              z32r, z32i);  // U stepper
        expz(ar2, airev, (float)(16 * nt),   vr,   vi);    // V start: z^(16nt)
        expz(ar2, airev, (float)(512 * mt),  tr_,  ti_);   // U start: z^(512mt)
        float ur = fmaf(cmr, tr_, -(cmi * ti_));           // u = Cm * z^(512mt)
        float ui = fmaf(cmr, ti_,   cmi * tr_);

        // U-gen: rows s = a_local, step z^32; store {Re, -Im} packed RTZ
#pragma unroll
        for (int s = 0; s < 16; ++s) {
            *(h16x2*)&sA[s][2 * n] = __builtin_amdgcn_cvt_pkrtz(ur, -ui);
            cmul(ur, ui, z32r, z32i);
        }
        // V-gen: rows s = b_local, step z; store {Re, Im} packed RTZ
#pragma unroll
        for (int s = 0; s < 16; ++s) {
            *(h16x2*)&sB[s][2 * n] = __builtin_amdgcn_cvt_pkrtz(vr, vi);
            cmul(vr, vi, z1r, z1i);
        }
    }
    // No __syncthreads: single wave; compiler inserts lgkmcnt before reads.

    // ---- MFMA: 16x16 tile, K = 128 ----
    const int mrow = n & 15;
    const int kgrp = n >> 4;
    f32x4 acc = {0.f, 0.f, 0.f, 0.f};
#pragma unroll
    for (int ks = 0; ks < 4; ++ks) {
        const int k0 = ks * 32 + kgrp * 8;            // 8 consecutive k per lane
        const f16x8 af = *(const f16x8*)&sA[mrow][k0];
        const f16x8 bf = *(const f16x8*)&sB[mrow][k0];
        acc = __builtin_amdgcn_mfma_f32_16x16x32_f16(af, bf, acc, 0, 0, 0);
    }

    // ---- epilogue: D col = mrow (b_local), row = kgrp*4 + r (a_local) ----
    float* o = out + h * Ldim + (16 * mt) * 32 + 16 * nt;
#pragma unroll
    for (int r = 0; r < 4; ++r)
        o[(kgrp * 4 + r) * 32 + mrow] = acc[r];
}

extern "C" void kernel_launch(void* const* d_in, const int* in_sizes, int n_in,
                              void* d_out, int out_size, void* d_ws, size_t ws_size,
                              hipStream_t stream) {
    // d_in order: L(scalar), log_dt, C_re, C_im, B_re, B_im, inv_A_real, A_imag
    const float* log_dt     = (const float*)d_in[1];
    const float* C_re       = (const float*)d_in[2];
    const float* C_im       = (const float*)d_in[3];
    const float* B_re       = (const float*)d_in[4];
    const float* B_im       = (const float*)d_in[5];
    const float* inv_A_real = (const float*)d_in[6];
    const float* A_imag     = (const float*)d_in[7];
    float* out = (float*)d_out;

    icmf_mfma<<<Hdim * 8, 64, 0, stream>>>(log_dt, C_re, C_im, B_re, B_im,
                                           inv_A_real, A_imag, out);
}

// Round 12
// 10.583 us; speedup vs baseline: 1.0369x; 1.0369x over previous
//
#include <hip/hip_runtime.h>

// ImplicitComplexModalFilter via single-pass FP16 MFMA factorization.
// K[h, 32a+b] = Re( sum_n U[a,n] * V[n,b] ),  U[a,n] = Cm_n * z_n^(32a) (64x64),
// V[n,b] = z_n^b (64x32), z_n = exp(dtA_n).
// Interleaved-complex K=128 contraction: A[a][2n]=Re U, A[a][2n+1]=-Im U;
// B^T[b][2n]=Re V, B^T[b][2n+1]=Im V  ->  sum_k A B = Re(U V).
// Round 12: revert to the best variant (R10, 10.49 us). Structural sweep
// R7/R9/R10/R11 (occupancy 16-32 waves/CU, -40% gen ops, 0-2 barriers,
// 64-512 thr blocks) all land 10.5-11.0 us vs ~2.5-3 us modeled work:
// the ~10.5 us is the dispatch floor, not a pipe limit.

typedef __attribute__((ext_vector_type(8))) _Float16 f16x8;
typedef __attribute__((ext_vector_type(2))) __fp16   h16x2;  // cvt_pkrtz result
typedef __attribute__((ext_vector_type(4))) float    f32x4;

#define Hdim 1024
#define Ndim 64
#define Ldim 2048
#define KPAD 136   // f16 units: 272B row stride, 16B-aligned, conflict-free b128
#define CPAD 36    // f32 units: 144B row stride, 16B-aligned, 2-way alias (free)

#define LOG2E  1.4426950408889634f
#define INV2PI 0.15915494309189535f

__device__ __forceinline__ void cmul(float& xr, float& xi, float yr, float yi) {
    const float tr = fmaf(xr, yr, -(xi * yi));
    xi = fmaf(xr, yi, xi * yr);
    xr = tr;
}

// z^t = exp(dtA * t) from ar2 = Re(dtA)*log2e, airev = Im(dtA)/2pi
__device__ __forceinline__ void expz(float ar2, float airev, float t,
                                     float& zr, float& zi) {
    const float e = __builtin_amdgcn_exp2f(ar2 * t);
    float f = airev * t;
    f -= floorf(f);
    zr = e * __builtin_amdgcn_cosf(f);
    zi = e * __builtin_amdgcn_sinf(f);
}

__global__ __launch_bounds__(512, 8) void icmf_mfma(
    const float* __restrict__ log_dt,
    const float* __restrict__ C_re, const float* __restrict__ C_im,
    const float* __restrict__ B_re, const float* __restrict__ B_im,
    const float* __restrict__ inv_A_real, const float* __restrict__ A_imag,
    float* __restrict__ out)
{
    __shared__ __align__(16) _Float16 sA[64][KPAD];  // [a][2n+(0:Re,1:-Im)] of U
    __shared__ __align__(16) _Float16 sB[32][KPAD];  // [b][2n+(0:Re,1: Im)] of V
    __shared__ __align__(16) float    sC[64][CPAD];  // staged output tile

    const int h   = blockIdx.x;
    const int tid = threadIdx.x;
    const int w   = tid >> 6;   // wave 0..7
    const int n   = tid & 63;   // lane = state index n

    // ---- per-(h,n) setup + per-wave chain anchors (direct evaluation) ----
    {
        const int idx = h * Ndim + n;
        const float dt = __builtin_amdgcn_exp2f(log_dt[h] * LOG2E);
        const float ar = -dt * __builtin_amdgcn_exp2f(inv_A_real[idx] * LOG2E);
        const float ai =  dt * A_imag[idx];
        // scale = dt / (1 - dtA/2)
        const float dre = 1.0f - 0.5f * ar;
        const float dim = -0.5f * ai;
        const float kk  = dt / (dre * dre + dim * dim);
        const float sre =  dre * kk;
        const float sim = -dim * kk;
        // Cm = 2 * B*C*scale (fold final 2x)
        const float br = B_re[idx], bi = B_im[idx];
        const float cr = C_re[idx], ci = C_im[idx];
        const float bcr = br * cr - bi * ci;
        const float bci = br * ci + bi * cr;
        const float cmr = 2.0f * (bcr * sre - bci * sim);
        const float cmi = 2.0f * (bcr * sim + bci * sre);
        const float ar2   = ar * LOG2E;
        const float airev = ai * INV2PI;

        // steppers + anchors: 4 independent direct evaluations
        float z1r, z1i, z32r, z32i, vr, vi, tr_, ti_;
        expz(ar2, airev, 1.0f,              z1r,  z1i);   // V stepper
        expz(ar2, airev, 32.0f,             z32r, z32i);  // U stepper
        expz(ar2, airev, (float)(4 * w),    vr,   vi);    // V start: z^(4w)
        expz(ar2, airev, (float)(256 * w),  tr_,  ti_);   // U start: z^(256w)
        float ur = fmaf(cmr, tr_, -(cmi * ti_));          // u = Cm * z^(256w)
        float ui = fmaf(cmr, ti_,   cmi * tr_);

        // U-gen: a = 8w + s, step z^32; store {Re, -Im} packed RTZ
#pragma unroll
        for (int s = 0; s < 8; ++s) {
            *(h16x2*)&sA[8 * w + s][2 * n] = __builtin_amdgcn_cvt_pkrtz(ur, -ui);
            cmul(ur, ui, z32r, z32i);
        }
        // V-gen: b = 4w + s, step z; store {Re, Im} packed RTZ
#pragma unroll
        for (int s = 0; s < 4; ++s) {
            *(h16x2*)&sB[4 * w + s][2 * n] = __builtin_amdgcn_cvt_pkrtz(vr, vi);
            cmul(vr, vi, z1r, z1i);
        }
    }
    __syncthreads();

    // ---- MFMA: wave w owns 16x16 tile (mt = w>>1, nt = w&1), K = 128 ----
    const int mt   = w >> 1;
    const int nt   = w & 1;
    const int mrow = n & 15;
    const int kgrp = n >> 4;
    f32x4 acc = {0.f, 0.f, 0.f, 0.f};
#pragma unroll
    for (int ks = 0; ks < 4; ++ks) {
        const int k0 = ks * 32 + kgrp * 8;              // 8 consecutive k per lane
        const f16x8 af = *(const f16x8*)&sA[16 * mt + mrow][k0];
        const f16x8 bf = *(const f16x8*)&sB[16 * nt + mrow][k0];
        acc = __builtin_amdgcn_mfma_f32_16x16x32_f16(af, bf, acc, 0, 0, 0);
    }

    // ---- stage to LDS (D: col = mrow -> b_local, row = kgrp*4+r -> a_local) ----
#pragma unroll
    for (int r = 0; r < 4; ++r)
        sC[16 * mt + kgrp * 4 + r][16 * nt + mrow] = acc[r];
    __syncthreads();

    // ---- coalesced epilogue: thread tid stores float4 at l = tid*4 ----
    {
        const f32x4 v = *(const f32x4*)&sC[tid >> 3][(tid & 7) * 4];
        *(f32x4*)(out + h * Ldim + tid * 4) = v;
    }
}

extern "C" void kernel_launch(void* const* d_in, const int* in_sizes, int n_in,
                              void* d_out, int out_size, void* d_ws, size_t ws_size,
                              hipStream_t stream) {
    // d_in order: L(scalar), log_dt, C_re, C_im, B_re, B_im, inv_A_real, A_imag
    const float* log_dt     = (const float*)d_in[1];
    const float* C_re       = (const float*)d_in[2];
    const float* C_im       = (const float*)d_in[3];
    const float* B_re       = (const float*)d_in[4];
    const float* B_im       = (const float*)d_in[5];
    const float* inv_A_real = (const float*)d_in[6];
    const float* A_imag     = (const float*)d_in[7];
    float* out = (float*)d_out;

    icmf_mfma<<<Hdim, 512, 0, stream>>>(log_dt, C_re, C_im, B_re, B_im,
                                        inv_A_real, A_imag, out);
}